// Round 12
// baseline (233.721 us; speedup 1.0000x reference)
//
#include <hip/hip_runtime.h>
#include <math.h>

// SALAD head. Round 17: gemm_fs col-split. Wave (cb,rb) computes rows
// rb*32..+31 x channels cb*96..+95: per kk reads 2 A + 6 B = 8 ds_read_b128
// for 12 MFMA (was 13 reads / 12 MFMA) -- 38% less LDS read traffic, the
// loop's dominant throughput term (R9 A/B proved it isn't stall-bound).
// u1-partials now 2x32-token (waves 2,3), merged 2-way. Rest = R11 verified.

#define BATCH 32
#define NTOK  1025
#define DIM   768
#define KDIM  64
#define CDIM  128
#define TDIM  256
#define NM1   1024
#define ROWLEN 8448          // TDIM + KDIM*CDIM
#define NITER 5
#define INV_REG 10.0f        // 1/0.1
#define NS_AGG 8             // n-slices in aggregation (128 tokens each)
#define LOG_A (-4.17438727f) // -log(65)
#define LOG_B (-6.93147181f) // -log(1024)

typedef __attribute__((ext_vector_type(8))) short short8;
typedef __attribute__((ext_vector_type(4))) float floatx4;

typedef __attribute__((address_space(3))) unsigned int lds_uint;
typedef const __attribute__((address_space(1))) unsigned int glb_uint;

__device__ __forceinline__ void gload_lds16(const void* g, void* l) {
    __builtin_amdgcn_global_load_lds((glb_uint*)g, (lds_uint*)l, 16, 0, 0);
}

__device__ __forceinline__ unsigned short bf16_rne(float f) {
    unsigned u = __builtin_bit_cast(unsigned, f);
    unsigned r = u + 0x7FFFu + ((u >> 16) & 1u);
    return (unsigned short)(r >> 16);
}

__device__ __forceinline__ short8 cvt8(float4 a, float4 b) {
    short8 r;
    r[0] = (short)bf16_rne(a.x); r[1] = (short)bf16_rne(a.y);
    r[2] = (short)bf16_rne(a.z); r[3] = (short)bf16_rne(a.w);
    r[4] = (short)bf16_rne(b.x); r[5] = (short)bf16_rne(b.y);
    r[6] = (short)bf16_rne(b.z); r[7] = (short)bf16_rne(b.w);
    return r;
}

// ---------------- prep: pack W (blocks 0..575) + t-GEMM (blocks 576..671) --
__global__ __launch_bounds__(256) void prep(
    const float* __restrict__ Wf, const float* __restrict__ Ws,
    const float* __restrict__ bf, const float* __restrict__ bs,
    const float* __restrict__ x, const float* __restrict__ Wt,
    short* __restrict__ W_pack, float* __restrict__ bias_all,
    float* __restrict__ tpart)
{
    __shared__ float xr[256];
    const int blk = blockIdx.x, tid = threadIdx.x;
    if (blk < 576) {
        int idx = blk * 256 + tid;   // < 147456 exactly
        int g    = idx / 6144;
        int rem  = idx - g * 6144;
        int nf   = rem >> 9;
        int rem2 = rem & 511;
        int lane = rem2 >> 3;
        int j    = rem2 & 7;
        int k = g * 32 + (lane >> 4) * 8 + j;
        int c = nf * 16 + (lane & 15);
        float v = (c < CDIM) ? Wf[(size_t)k * CDIM + c] : Ws[(size_t)k * KDIM + (c - CDIM)];
        W_pack[idx] = (short)bf16_rne(v);
        if (idx < 192) bias_all[idx] = (idx < CDIM) ? bf[idx] : bs[idx - CDIM];
    } else {
        int i = blk - 576;           // 0..95
        int b = i / 3, dy = i - b * 3;
        xr[tid] = x[(size_t)b * NTOK * DIM + (size_t)dy * 256 + tid];
        __syncthreads();
        float acc = 0.f;
        const float* wp = Wt + (size_t)dy * 256 * TDIM + tid;
#pragma unroll 8
        for (int d = 0; d < 256; ++d) acc = fmaf(xr[d], wp[(size_t)d * TDIM], acc);
        tpart[((size_t)dy * BATCH + b) * TDIM + tid] = acc;
    }
}

// ---------------- fused f / s GEMM via MFMA + LDS staging -------------------
// blockIdx = [chunk 0..15][b 0..31] (XCD pinned). Wave (cb=w>>1, rb=w&1):
// rows rb*32..+31, channels cb*96..+95 (6 nf). As layout [kk][rblk][lane][8].
// Epilogue: s-part in cb=1 waves j>=2; u1-partials 2x32-token, 2-way merge.
__global__ __launch_bounds__(256, 2) void gemm_fs(
    const float* __restrict__ x, const short* __restrict__ W_pack,
    const float* __restrict__ bias_all, const float* __restrict__ sharp_p,
    const float* __restrict__ dust_p,
    unsigned short* __restrict__ fT, float* __restrict__ Mmat,
    float2* __restrict__ part0)
{
    __shared__ __align__(16) short Bs[12288];  // 24 KB [kk][nf][lane][8]
    __shared__ __align__(16) short As[4096];   //  8 KB [kk][rblk][lane][8]
    __shared__ float2 sm[2][4][16];            // [rb][j-2][lrow]
    const int tid  = threadIdx.x;
    const int wave = tid >> 6, lane = tid & 63;
    const int quad = lane >> 4, lrow = lane & 15;
    const int cb = wave >> 1, rb = wave & 1;
    const int bb0   = blockIdx.x & 31;
    const int chunk = blockIdx.x >> 5;       // 0..15

    // x staging: thread stages row r2 = tid>>2 (0..63), k-seg (tid&3)*16
    const int arow = bb0 * 1024 + chunk * 64 + (tid >> 2);
    const float* asrc = x + ((size_t)(arow >> 10) * NTOK + 1 + (arow & 1023)) * DIM + (tid & 3) * 16;
    const int r2   = tid >> 2;
    const int seg  = tid & 3;
    const int kk_w = seg >> 1;
    const int q0   = (seg & 1) * 2;
    short* adst0 = &As[((kk_w * 4 + (r2 >> 4)) * 64 + q0 * 16 + (r2 & 15)) * 8];
    short* adst1 = &As[((kk_w * 4 + (r2 >> 4)) * 64 + (q0 + 1) * 16 + (r2 & 15)) * 8];

    floatx4 acc[2][6];
#pragma unroll
    for (int i = 0; i < 2; ++i)
#pragma unroll
        for (int j = 0; j < 6; ++j) acc[i][j] = (floatx4){0.f, 0.f, 0.f, 0.f};

    float4 g0 = *(const float4*)(asrc);
    float4 g1 = *(const float4*)(asrc + 4);
    float4 g2 = *(const float4*)(asrc + 8);
    float4 g3 = *(const float4*)(asrc + 12);

    for (int ko = 0; ko < 12; ++ko) {
        __syncthreads();
        const short* bsrc = W_pack + ko * 12288 + tid * 8;
#pragma unroll
        for (int i = 0; i < 6; ++i)
            gload_lds16(bsrc + i * 2048, &Bs[i * 2048 + tid * 8]);
        *(short8*)adst0 = cvt8(g0, g1);
        *(short8*)adst1 = cvt8(g2, g3);
        __syncthreads();
        if (ko < 11) {
            // prefetch next x k-slice after the barrier: HBM latency overlaps
            // the MFMA phase; drained by NEXT iteration's barrier (R7 win).
            const float* ap = asrc + (ko + 1) * 64;
            g0 = *(const float4*)(ap);
            g1 = *(const float4*)(ap + 4);
            g2 = *(const float4*)(ap + 8);
            g3 = *(const float4*)(ap + 12);
            __builtin_amdgcn_sched_barrier(0);  // loads may not sink below
        }
#pragma unroll
        for (int kk = 0; kk < 2; ++kk) {
            short8 a0 = *(const short8*)&As[((kk * 4 + rb * 2 + 0) * 64 + lane) * 8];
            short8 a1 = *(const short8*)&As[((kk * 4 + rb * 2 + 1) * 64 + lane) * 8];
#pragma unroll
            for (int j = 0; j < 6; ++j) {
                const int nf = cb * 6 + j;
                short8 bf8 = *(const short8*)&Bs[((kk * 12 + nf) * 64 + lane) * 8];
                acc[0][j] = __builtin_amdgcn_mfma_f32_16x16x32_bf16(a0, bf8, acc[0][j], 0, 0, 0);
                acc[1][j] = __builtin_amdgcn_mfma_f32_16x16x32_bf16(a1, bf8, acc[1][j], 0, 0, 0);
            }
        }
    }

    const float sc = sharp_p[0] * INV_REG;
    const float dustM = dust_p[0] * INV_REG;
    const int tokb = chunk * 64 + rb * 32 + quad * 4;
#pragma unroll
    for (int j = 0; j < 6; ++j) {
        const int c = cb * 96 + j * 16 + lrow;
        const float bias = bias_all[c];
        if (c < CDIM) {
            // f part: bf16 transposed store, 4 tokens per i-block
#pragma unroll
            for (int i = 0; i < 2; ++i) {
                ushort4 w;
                w.x = bf16_rne(acc[i][j][0] + bias);
                w.y = bf16_rne(acc[i][j][1] + bias);
                w.z = bf16_rne(acc[i][j][2] + bias);
                w.w = bf16_rne(acc[i][j][3] + bias);
                *(ushort4*)(fT + ((size_t)bb0 * CDIM + c) * NM1 + tokb + i * 16) = w;
            }
        } else {
            const int k = c - CDIM;
            float mM = -3.4e38f;
            float vv[2][4];
#pragma unroll
            for (int i = 0; i < 2; ++i) {
                float4 w = make_float4((acc[i][j][0] + bias) * sc, (acc[i][j][1] + bias) * sc,
                                       (acc[i][j][2] + bias) * sc, (acc[i][j][3] + bias) * sc);
                *(float4*)(Mmat + ((size_t)bb0 * KDIM + k) * NM1 + tokb + i * 16) = w;
                vv[i][0] = w.x; vv[i][1] = w.y; vv[i][2] = w.z; vv[i][3] = w.w;
                mM = fmaxf(mM, fmaxf(fmaxf(w.x, w.y), fmaxf(w.z, w.w)));
            }
            // u1-partial: row-LSE over this wave's 32 tokens (v0 = 0)
            mM = fmaxf(mM, __shfl_xor(mM, 16));
            mM = fmaxf(mM, __shfl_xor(mM, 32));
            float e = 0.f;
#pragma unroll
            for (int i = 0; i < 2; ++i)
#pragma unroll
                for (int q = 0; q < 4; ++q) e += __expf(vv[i][q] - mM);
            e += __shfl_xor(e, 16);
            e += __shfl_xor(e, 32);
            if (quad == 0) sm[rb][j - 2][lrow] = make_float2(mM, e);
        }
    }
    __syncthreads();
    // combine 2 row-block partials (64 tokens) -> part0[b][chunk][k]
    if (tid < 65) {
        float2 o;
        if (tid < 64) {
            float2 p0 = sm[0][tid >> 4][tid & 15];
            float2 p1 = sm[1][tid >> 4][tid & 15];
            float m = fmaxf(p0.x, p1.x);
            float e = p0.y * __expf(p0.x - m) + p1.y * __expf(p1.x - m);
            o = make_float2(m, e);
        } else {
            o = make_float2(dustM, 64.f);   // dust row, v0=0: 64 tokens exp(0)
        }
        part0[((size_t)bb0 * 16 + chunk) * 65 + tid] = o;
    }
}

// ---------------- sink_vu: one dispatch per sinkhorn iteration --------------
// 512 blocks = [ns2 0..15][b 0..31] x 256 thr. Thread (tok = tid&63,
// kq = tid>>6). Phase 1: combine 16 u-partials -> us[65]. Phase 2: v-update
// (coalesced M in regs, 4-way LDS combine + dust). Phase 3: emit next
// u-partials via LDS transpose yb[64][65] + 4-lane shfl (m,e) merge.
__global__ __launch_bounds__(256) void sink_vu(
    const float* __restrict__ Mmat, const float* __restrict__ dust_p,
    const float2* __restrict__ pin, float2* __restrict__ pout)
{
    __shared__ float us[65];
    __shared__ float2 pp[4][64];
    __shared__ float vsh[64];
    __shared__ float yb[64][65];
    const int b   = blockIdx.x & 31;
    const int ns2 = blockIdx.x >> 5;         // 0..15
    const int tid = threadIdx.x;
    const int tok = tid & 63, kq = tid >> 6;
    const int n = ns2 * 64 + tok;
    const float dustM = dust_p[0] * INV_REG;

    // coalesced M loads: mreg[kk] = M[b][kq*16+kk][n]
    float mreg[16];
    const float* Mb = Mmat + ((size_t)b * KDIM + kq * 16) * NM1 + n;
#pragma unroll
    for (int kk = 0; kk < 16; ++kk) mreg[kk] = Mb[(size_t)kk * NM1];

    // ---- phase 1: u-combine (16 chunk partials) ----
    if (tid < 65) {
        const float2* pr = pin + (size_t)b * 16 * 65 + tid;
        float M2 = -3.4e38f;
        float2 pv[16];
#pragma unroll
        for (int q = 0; q < 16; ++q) { pv[q] = pr[q * 65]; M2 = fmaxf(M2, pv[q].x); }
        float S2 = 0.f;
#pragma unroll
        for (int q = 0; q < 16; ++q) S2 += pv[q].y * __expf(pv[q].x - M2);
        us[tid] = LOG_A - (M2 + __logf(S2));
    }
    __syncthreads();

    // ---- phase 2: v-update ----
    {
        float m = mreg[0] + us[kq * 16];
#pragma unroll
        for (int kk = 1; kk < 16; ++kk) m = fmaxf(m, mreg[kk] + us[kq * 16 + kk]);
        float e = 0.f;
#pragma unroll
        for (int kk = 0; kk < 16; ++kk) e += __expf(mreg[kk] + us[kq * 16 + kk] - m);
        pp[kq][tok] = make_float2(m, e);
    }
    __syncthreads();
    if (tid < 64) {
        const float xd = dustM + us[64];
        float m3 = xd;
#pragma unroll
        for (int q = 0; q < 4; ++q) m3 = fmaxf(m3, pp[q][tid].x);
        float S3 = __expf(xd - m3);
#pragma unroll
        for (int q = 0; q < 4; ++q) S3 += pp[q][tid].y * __expf(pp[q][tid].x - m3);
        vsh[tid] = LOG_B - (m3 + __logf(S3));
    }
    __syncthreads();

    // ---- phase 3: emit next u-partials ----
    const float v = vsh[tok];
#pragma unroll
    for (int kk = 0; kk < 16; ++kk) yb[kq * 16 + kk][tok] = mreg[kk] + v;
    // dust partial: LSE over this block's 64 tokens of (dustM + v[t]); wave 0
    if (kq == 0) {
        float mv = v;
#pragma unroll
        for (int off = 1; off < 64; off <<= 1) mv = fmaxf(mv, __shfl_xor(mv, off));
        float ev = __expf(v - mv);
#pragma unroll
        for (int off = 1; off < 64; off <<= 1) ev += __shfl_xor(ev, off);
        if (tok == 0) pout[((size_t)b * 16 + ns2) * 65 + 64] = make_float2(dustM + mv, ev);
    }
    __syncthreads();
    // transposed per-row reduce: row r = tid>>2 (0..63), quarter tq = tid&3
    {
        const int rr = tid >> 2, tq = tid & 3;
        float mm = yb[rr][tq * 16];
#pragma unroll
        for (int i = 1; i < 16; ++i) mm = fmaxf(mm, yb[rr][tq * 16 + i]);
        float ee = 0.f;
#pragma unroll
        for (int i = 0; i < 16; ++i) ee += __expf(yb[rr][tq * 16 + i] - mm);
        // merge (m,e) across the 4 same-row lanes (consecutive, same wave)
        float m1 = __shfl_xor(mm, 1), e1 = __shfl_xor(ee, 1);
        float mo = fmaxf(mm, m1);
        ee = ee * __expf(mm - mo) + e1 * __expf(m1 - mo); mm = mo;
        float m2 = __shfl_xor(mm, 2), e2 = __shfl_xor(ee, 2);
        mo = fmaxf(mm, m2);
        ee = ee * __expf(mm - mo) + e2 * __expf(m2 - mo); mm = mo;
        if (tq == 0) pout[((size_t)b * 16 + ns2) * 65 + rr] = make_float2(mm, ee);
    }
}

// ---------------- aggregation: u5-combine (16 parts) + v5 + MFMA ------------
// grid (BATCH, NS_AGG) x 256 thr. M-slice in A-frag regs; v5 computed
// block-locally from u5; then p = exp(M+u+v) -> MFMA vs fT B-frags.
__global__ __launch_bounds__(256) void aggregate(
    const float* __restrict__ Mmat, const unsigned short* __restrict__ fT,
    const float2* __restrict__ pin, const float* __restrict__ dust_p,
    float* __restrict__ vpart, float* __restrict__ rspart)
{
    __shared__ float us[65];
    __shared__ __align__(16) float vsh[128];
    __shared__ float wv[4][128][2];
    const int b = blockIdx.x, ns = blockIdx.y;
    const int tid = threadIdx.x;
    const int wave = tid >> 6, lane = tid & 63;
    const int quad = lane >> 4, lrow = lane & 15;
    const int krow = wave * 16 + lrow;
    const float dustM = dust_p[0] * INV_REG;

    // ---- u5 combine (16 chunk partials) ----
    if (tid < 65) {
        const float2* pr = pin + (size_t)b * 16 * 65 + tid;
        float M2 = -3.4e38f;
        float2 pv[16];
#pragma unroll
        for (int q = 0; q < 16; ++q) { pv[q] = pr[q * 65]; M2 = fmaxf(M2, pv[q].x); }
        float S2 = 0.f;
#pragma unroll
        for (int q = 0; q < 16; ++q) S2 += pv[q].y * __expf(pv[q].x - M2);
        us[tid] = LOG_A - (M2 + __logf(S2));
    }
    __syncthreads();

    // ---- M slice into registers (A-frag layout) ----
    float mreg[32];
    {
        const float* Mrow = Mmat + ((size_t)b * KDIM + krow) * NM1 + ns * 128 + quad * 8;
#pragma unroll
        for (int s = 0; s < 4; ++s) {
            float4 a = *(const float4*)(Mrow + s * 32);
            float4 c = *(const float4*)(Mrow + s * 32 + 4);
            mreg[s*8+0]=a.x; mreg[s*8+1]=a.y; mreg[s*8+2]=a.z; mreg[s*8+3]=a.w;
            mreg[s*8+4]=c.x; mreg[s*8+5]=c.y; mreg[s*8+6]=c.z; mreg[s*8+7]=c.w;
        }
    }

    // ---- fused v5: v[t] = LOG_B - LSE_k(M[k][t] + u[k]) ----
    const float uk = us[krow];
#pragma unroll
    for (int s = 0; s < 4; ++s) {
#pragma unroll
        for (int j = 0; j < 8; ++j) {
            float x = mreg[s*8+j] + uk;
            float m2 = x;
            m2 = fmaxf(m2, __shfl_xor(m2, 1));
            m2 = fmaxf(m2, __shfl_xor(m2, 2));
            m2 = fmaxf(m2, __shfl_xor(m2, 4));
            m2 = fmaxf(m2, __shfl_xor(m2, 8));
            float e = __expf(x - m2);
            e += __shfl_xor(e, 1);
            e += __shfl_xor(e, 2);
            e += __shfl_xor(e, 4);
            e += __shfl_xor(e, 8);
            if (lrow == 0) {
                wv[wave][s*32 + quad*8 + j][0] = m2;
                wv[wave][s*32 + quad*8 + j][1] = e;
            }
        }
    }
    __syncthreads();
    if (tid < 128) {
        const float xd = dustM + us[64];
        float m3 = xd;
#pragma unroll
        for (int w = 0; w < 4; ++w) m3 = fmaxf(m3, wv[w][tid][0]);
        float S3 = __expf(xd - m3);
#pragma unroll
        for (int w = 0; w < 4; ++w) S3 += wv[w][tid][1] * __expf(wv[w][tid][0] - m3);
        vsh[tid] = LOG_B - (m3 + __logf(S3));
    }
    __syncthreads();

    // ---- p = exp(M+u+v) in A-frag regs, MFMA vs fT B-frags ----
    const unsigned short* fbase = fT + ((size_t)b * CDIM + lrow) * NM1 + ns * 128 + quad * 8;
    floatx4 acc[8];
#pragma unroll
    for (int nf = 0; nf < 8; ++nf) acc[nf] = (floatx4){0.f, 0.f, 0.f, 0.f};
    float rs = 0.f;
#pragma unroll
    for (int s = 0; s < 4; ++s) {
        const int tb = s * 32 + quad * 8;
        float4 v0 = *(const float4*)&vsh[tb];
        float4 v1 = *(const float4*)&vsh[tb + 4];
        float p[8];
        p[0] = __expf(mreg[s*8+0] + uk + v0.x);
        p[1] = __expf(mreg[s*8+1] + uk + v0.y);
        p[2] = __expf(mreg[s*8+2] + uk + v0.z);
        p[3] = __expf(mreg[s*8+3] + uk + v0.w);
        p[4] = __expf(mreg[s*8+4] + uk + v1.x);
        p[5] = __expf(mreg[s*8+5] + uk + v1.y);
        p[6] = __expf(mreg[s*8+6] + uk + v1.z);
        p[7] = __expf(mreg[s*8+7] + uk + v1.w);
        short8 afrag;
#pragma unroll
        for (int j = 0; j < 8; ++j) {
            rs += p[j];
            afrag[j] = (short)bf16_rne(p[j]);
        }
#pragma unroll
        for (int nf = 0; nf < 8; ++nf) {
            short8 bfrag = *(const short8*)(fbase + (size_t)nf * 16 * NM1 + s * 32);
            acc[nf] = __builtin_amdgcn_mfma_f32_16x16x32_bf16(afrag, bfrag, acc[nf], 0, 0, 0);
        }
    }
    rs += __shfl_xor(rs, 16);
    rs += __shfl_xor(rs, 32);
    if (lane < 16) rspart[(ns * BATCH + b) * KDIM + krow] = rs;

    float* vp = vpart + (size_t)(ns * BATCH + b) * (KDIM * CDIM);
#pragma unroll
    for (int nf = 0; nf < 8; ++nf) {
        const int c = nf * 16 + lrow;
#pragma unroll
        for (int j = 0; j < 4; ++j)
            vp[(size_t)(wave * 16 + quad * 4 + j) * CDIM + c] = acc[nf][j];
    }
}

// ---------------- finalize: reduce partials, anchors, L2-normalize ---------
__global__ __launch_bounds__(1024) void finalize_all(
    const float* __restrict__ vpart, const float* __restrict__ rspart,
    const float* __restrict__ anchors, const float* __restrict__ tpart,
    const float* __restrict__ bt, float* __restrict__ out)
{
    __shared__ float rstot[KDIM];
    __shared__ float red[16];
    __shared__ float sc_sh;
    const int b = blockIdx.x, tid = threadIdx.x;
    const int lane = tid & 63, wave = tid >> 6;

    if (tid < KDIM) {
        float s = 0.f;
#pragma unroll
        for (int ns = 0; ns < NS_AGG; ++ns)
            s += rspart[(ns * BATCH + b) * KDIM + tid];
        rstot[tid] = s;
    }
    __syncthreads();

    const size_t e0 = (size_t)tid * 8;
    float4 s0 = make_float4(0.f, 0.f, 0.f, 0.f);
    float4 s1 = make_float4(0.f, 0.f, 0.f, 0.f);
#pragma unroll
    for (int ns = 0; ns < NS_AGG; ++ns) {
        const float* vp = vpart + (size_t)(ns * BATCH + b) * (KDIM * CDIM) + e0;
        float4 a = *(const float4*)(vp);
        float4 c = *(const float4*)(vp + 4);
        s0.x += a.x; s0.y += a.y; s0.z += a.z; s0.w += a.w;
        s1.x += c.x; s1.y += c.y; s1.z += c.z; s1.w += c.w;
    }
    const float rsv = rstot[tid >> 4];
    float4 a0 = *(const float4*)(anchors + e0);
    float4 a1 = *(const float4*)(anchors + e0 + 4);
    float4 v0, v1;
    v0.x = 2.f * s0.x - rsv * a0.x;  v0.y = 2.f * s0.y - rsv * a0.y;
    v0.z = 2.f * s0.z - rsv * a0.z;  v0.w = 2.f * s0.w - rsv * a0.w;
    v1.x = 2.f * s1.x - rsv * a1.x;  v1.y = 2.f * s1.y - rsv * a1.y;
    v1.z = 2.f * s1.z - rsv * a1.z;  v1.w = 2.f * s1.w - rsv * a1.w;
    float ss = v0.x*v0.x + v0.y*v0.y + v0.z*v0.z + v0.w*v0.w
             + v1.x*v1.x + v1.y*v1.y + v1.z*v1.z + v1.w*v1.w;

    float t = 0.f;
    if (tid < TDIM) {
        t = bt[tid];
#pragma unroll
        for (int s = 0; s < 3; ++s) t += tpart[((size_t)s * BATCH + b) * TDIM + tid];
        ss += t * t;
    }

#pragma unroll
    for (int off = 32; off > 0; off >>= 1) ss += __shfl_down(ss, off);
    if (lane == 0) red[wave] = ss;
    __syncthreads();
    if (tid == 0) {
        float tot = 0.f;
#pragma unroll
        for (int i = 0; i < 16; ++i) tot += red[i];
        sc_sh = 1.f / fmaxf(sqrtf(tot), 1e-12f);
    }
    __syncthreads();
    const float scale = sc_sh;

    float* orow = out + (size_t)b * ROWLEN;
    if (tid < TDIM) orow[tid] = t * scale;
    v0.x *= scale; v0.y *= scale; v0.z *= scale; v0.w *= scale;
    v1.x *= scale; v1.y *= scale; v1.z *= scale; v1.w *= scale;
    *(float4*)&orow[TDIM + e0]     = v0;
    *(float4*)&orow[TDIM + e0 + 4] = v1;
}

// ---------------- launcher ----------------
extern "C" void kernel_launch(void* const* d_in, const int* in_sizes, int n_in,
                              void* d_out, int out_size, void* d_ws, size_t ws_size,
                              hipStream_t stream)
{
    const float* x       = (const float*)d_in[0];
    const float* Wf      = (const float*)d_in[1];
    const float* bf      = (const float*)d_in[2];
    const float* Ws      = (const float*)d_in[3];
    const float* bs      = (const float*)d_in[4];
    const float* Wt      = (const float*)d_in[5];
    const float* bt      = (const float*)d_in[6];
    const float* anchors = (const float*)d_in[7];
    const float* dust    = (const float*)d_in[8];
    const float* sharp   = (const float*)d_in[9];
    float* out = (float*)d_out;

    char* base = (char*)d_ws;
    short* W_pack        = (short*)base;                       // 294912 B
    float* bias_all      = (float*)(base + 294912);            // 192 fl
    float* Mmat          = bias_all + 192;                     // 2097152 fl (8.39 MB)
    unsigned short* fT   = (unsigned short*)(Mmat + (size_t)BATCH * KDIM * NM1); // 4194304 us
    float2* part0        = (float2*)(fT + (size_t)BATCH * CDIM * NM1); // 32*16*65 f2
    float2* part1        = part0 + (size_t)BATCH * 16 * 65;
    float* vpart         = (float*)(part1 + (size_t)BATCH * 16 * 65); // 2097152 fl
    float* rspart        = vpart + (size_t)NS_AGG * BATCH * KDIM * CDIM; // 16384 fl
    float* tpart         = rspart + NS_AGG * BATCH * KDIM;     // 24576 fl

    hipLaunchKernelGGL(prep, dim3(672), dim3(256), 0, stream,
                       Wf, Ws, bf, bs, x, Wt, W_pack, bias_all, tpart);
    hipLaunchKernelGGL(gemm_fs, dim3(512), dim3(256), 0, stream,
                       x, W_pack, bias_all, sharp, dust, fT, Mmat, part0);

    // 4 fused iterations: combine u_it, compute v_it, emit u_{it+1}-partials
    hipLaunchKernelGGL(sink_vu, dim3(512), dim3(256), 0, stream,
                       Mmat, dust, part0, part1);
    hipLaunchKernelGGL(sink_vu, dim3(512), dim3(256), 0, stream,
                       Mmat, dust, part1, part0);
    hipLaunchKernelGGL(sink_vu, dim3(512), dim3(256), 0, stream,
                       Mmat, dust, part0, part1);
    hipLaunchKernelGGL(sink_vu, dim3(512), dim3(256), 0, stream,
                       Mmat, dust, part1, part0);

    // u5 combine + v5 + aggregation MFMA
    hipLaunchKernelGGL(aggregate, dim3(BATCH, NS_AGG), dim3(256), 0, stream,
                       Mmat, fT, part0, dust, vpart, rspart);
    hipLaunchKernelGGL(finalize_all, dim3(BATCH), dim3(1024), 0, stream,
                       vpart, rspart, anchors, tpart, bt, out);
}